// Round 1
// baseline (577.897 us; speedup 1.0000x reference)
//
#include <hip/hip_runtime.h>

#define N_NODES 50000
#define N_EDGES 800000
#define DIM 64
#define ODIM 32
#define N_GRAPHS 512

// ---- graph prep: counting-sort edges by dst into CSR ----

__global__ void count_deg(const int* __restrict__ dst, int* __restrict__ cnt) {
    int e = blockIdx.x * blockDim.x + threadIdx.x;
    if (e < N_EDGES) atomicAdd(&cnt[dst[e]], 1);
}

__global__ void compute_norm(const int* __restrict__ cnt,
                             float* __restrict__ inv_sqrt, float* __restrict__ invdeg) {
    int i = blockIdx.x * blockDim.x + threadIdx.x;
    if (i < N_NODES) {
        float d = (float)(cnt[i] + 1);   // self-loop
        inv_sqrt[i] = rsqrtf(d);
        invdeg[i]   = 1.0f / d;
    }
}

// single-block Hillis-Steele scan over 50k counts -> exclusive offsets (+cursor copy)
__global__ void scan_offsets(const int* __restrict__ cnt,
                             int* __restrict__ off, int* __restrict__ cursor) {
    __shared__ int sh[1024];
    __shared__ int carry_s;
    if (threadIdx.x == 0) carry_s = 0;
    __syncthreads();
    for (int base = 0; base < N_NODES; base += 1024) {
        int i = base + threadIdx.x;
        int v = (i < N_NODES) ? cnt[i] : 0;
        sh[threadIdx.x] = v;
        __syncthreads();
        for (int d = 1; d < 1024; d <<= 1) {
            int t = (threadIdx.x >= d) ? sh[threadIdx.x - d] : 0;
            __syncthreads();
            sh[threadIdx.x] += t;
            __syncthreads();
        }
        int incl  = sh[threadIdx.x];
        int total = sh[1023];
        __syncthreads();
        if (i < N_NODES) { int o = carry_s + incl - v; off[i] = o; cursor[i] = o; }
        __syncthreads();
        if (threadIdx.x == 0) carry_s += total;
        __syncthreads();
    }
    if (threadIdx.x == 0) off[N_NODES] = carry_s;
}

__global__ void scatter_edges(const int* __restrict__ src, const int* __restrict__ dst,
                              int* __restrict__ cursor, int* __restrict__ srcs) {
    int e = blockIdx.x * blockDim.x + threadIdx.x;
    if (e < N_EDGES) {
        int d = dst[e];
        int pos = atomicAdd(&cursor[d], 1);
        srcs[pos] = src[e];
    }
}

// ---- h = X @ W  (N x 64 @ 64 x 64), W staged in LDS, 8 rows per wave ----

__global__ __launch_bounds__(256) void gemm64(const float* __restrict__ X,
                                              const float* __restrict__ W,
                                              float* __restrict__ Y, int nrows) {
    __shared__ float Ws[64 * 64];
    for (int i = threadIdx.x; i < 64 * 64; i += 256) Ws[i] = W[i];
    __syncthreads();
    int wave = threadIdx.x >> 6;
    int j    = threadIdx.x & 63;
    int row0 = (blockIdx.x * 4 + wave) * 8;
    for (int r = 0; r < 8; ++r) {
        int row = row0 + r;
        if (row >= nrows) return;
        const float* xr = X + (size_t)row * DIM;
        float acc = 0.f;
#pragma unroll
        for (int k = 0; k < DIM; ++k) acc = fmaf(xr[k], Ws[k * DIM + j], acc);
        Y[(size_t)row * DIM + j] = acc;
    }
}

// ---- out[i] = relu( sum_{e:dst=i} h[src]*norm + h[i]/deg_i + b ) ----
// one wave per node, lane = feature; gather-style, no atomics

__global__ __launch_bounds__(256) void aggregate(const float* __restrict__ H,
                                                 const int* __restrict__ off,
                                                 const int* __restrict__ srcs,
                                                 const float* __restrict__ inv_sqrt,
                                                 const float* __restrict__ invdeg,
                                                 const float* __restrict__ bias,
                                                 float* __restrict__ Y) {
    int node = blockIdx.x * 4 + (threadIdx.x >> 6);
    int j    = threadIdx.x & 63;
    if (node >= N_NODES) return;
    float isd = inv_sqrt[node];
    float acc = H[(size_t)node * DIM + j] * invdeg[node];
    int s0 = off[node], s1 = off[node + 1];
    for (int k = s0; k < s1; ++k) {
        int s = srcs[k];
        float w = inv_sqrt[s] * isd;
        acc = fmaf(H[(size_t)s * DIM + j], w, acc);
    }
    acc += bias[j];
    Y[(size_t)node * DIM + j] = fmaxf(acc, 0.f);
}

// ---- global mean pool (atomic accumulate) ----

__global__ __launch_bounds__(256) void pool(const float* __restrict__ H,
                                            const int* __restrict__ batch,
                                            float* __restrict__ sums,
                                            float* __restrict__ gcnt) {
    int node = blockIdx.x * 4 + (threadIdx.x >> 6);
    int j    = threadIdx.x & 63;
    if (node >= N_NODES) return;
    int g = batch[node];
    atomicAdd(&sums[g * DIM + j], H[(size_t)node * DIM + j]);
    if (j == 0) atomicAdd(&gcnt[g], 1.0f);
}

// ---- out = (sums/cnt) @ fcW + fcb ;  2 graphs per 64-thread block ----

__global__ void fc(const float* __restrict__ sums, const float* __restrict__ gcnt,
                   const float* __restrict__ fcW, const float* __restrict__ fcb,
                   float* __restrict__ out) {
    int t  = threadIdx.x;
    int g  = blockIdx.x * 2 + (t >> 5);
    int jj = t & 31;
    if (g >= N_GRAPHS) return;
    float c = fmaxf(gcnt[g], 1.0f);
    float inv = 1.0f / c;
    float acc = fcb[jj];
#pragma unroll
    for (int k = 0; k < DIM; ++k)
        acc = fmaf(sums[g * DIM + k] * inv, fcW[k * ODIM + jj], acc);
    out[g * ODIM + jj] = acc;
}

extern "C" void kernel_launch(void* const* d_in, const int* in_sizes, int n_in,
                              void* d_out, int out_size, void* d_ws, size_t ws_size,
                              hipStream_t stream) {
    const float* x    = (const float*)d_in[0];
    const float* W1   = (const float*)d_in[1];
    const float* b1   = (const float*)d_in[2];
    const float* W2   = (const float*)d_in[3];
    const float* b2   = (const float*)d_in[4];
    const float* fcW  = (const float*)d_in[5];
    const float* fcb  = (const float*)d_in[6];
    const int*   eidx = (const int*)d_in[7];
    const int*   batch= (const int*)d_in[8];
    const int* esrc = eidx;
    const int* edst = eidx + N_EDGES;
    float* out = (float*)d_out;

    char* ws = (char*)d_ws;
    size_t o = 0;
    auto alloc = [&](size_t bytes) {
        void* p = ws + o;
        o += (bytes + 255) & ~(size_t)255;
        return p;
    };
    float* bufA     = (float*)alloc((size_t)N_NODES * DIM * 4);
    float* bufB     = (float*)alloc((size_t)N_NODES * DIM * 4);
    int*   cnt      = (int*)  alloc((size_t)N_NODES * 4);
    int*   off      = (int*)  alloc((size_t)(N_NODES + 1) * 4);
    int*   cursor   = (int*)  alloc((size_t)N_NODES * 4);
    float* inv_sqrt = (float*)alloc((size_t)N_NODES * 4);
    float* invdeg   = (float*)alloc((size_t)N_NODES * 4);
    int*   srcs     = (int*)  alloc((size_t)N_EDGES * 4);
    float* sums     = (float*)alloc((size_t)N_GRAPHS * DIM * 4);
    float* gcnt     = (float*)alloc((size_t)N_GRAPHS * 4);

    hipMemsetAsync(cnt,  0, (size_t)N_NODES * 4, stream);
    hipMemsetAsync(sums, 0, (size_t)N_GRAPHS * DIM * 4, stream);
    hipMemsetAsync(gcnt, 0, (size_t)N_GRAPHS * 4, stream);

    count_deg<<<(N_EDGES + 255) / 256, 256, 0, stream>>>(edst, cnt);
    compute_norm<<<(N_NODES + 255) / 256, 256, 0, stream>>>(cnt, inv_sqrt, invdeg);
    scan_offsets<<<1, 1024, 0, stream>>>(cnt, off, cursor);
    scatter_edges<<<(N_EDGES + 255) / 256, 256, 0, stream>>>(esrc, edst, cursor, srcs);

    gemm64<<<(N_NODES + 31) / 32, 256, 0, stream>>>(x, W1, bufA, N_NODES);
    aggregate<<<(N_NODES + 3) / 4, 256, 0, stream>>>(bufA, off, srcs, inv_sqrt, invdeg, b1, bufB);
    gemm64<<<(N_NODES + 31) / 32, 256, 0, stream>>>(bufB, W2, bufA, N_NODES);
    aggregate<<<(N_NODES + 3) / 4, 256, 0, stream>>>(bufA, off, srcs, inv_sqrt, invdeg, b2, bufB);

    pool<<<(N_NODES + 3) / 4, 256, 0, stream>>>(bufB, batch, sums, gcnt);
    fc<<<(N_GRAPHS + 1) / 2, 64, 0, stream>>>(sums, gcnt, fcW, fcb, out);
}

// Round 2
// 509.205 us; speedup vs baseline: 1.1349x; 1.1349x over previous
//
#include <hip/hip_runtime.h>

#define N_NODES 50000
#define N_EDGES 800000
#define DIM 64
#define ODIM 32
#define N_GRAPHS 512

// ---- graph prep: counting-sort edges by dst into CSR ----

__global__ void count_deg(const int* __restrict__ dst, int* __restrict__ cnt) {
    int e = blockIdx.x * blockDim.x + threadIdx.x;
    if (e < N_EDGES) atomicAdd(&cnt[dst[e]], 1);
}

__global__ void compute_norm(const int* __restrict__ cnt,
                             float* __restrict__ inv_sqrt, float* __restrict__ invdeg) {
    int i = blockIdx.x * blockDim.x + threadIdx.x;
    if (i < N_NODES) {
        float d = (float)(cnt[i] + 1);   // self-loop
        inv_sqrt[i] = rsqrtf(d);
        invdeg[i]   = 1.0f / d;
    }
}

// chunked exclusive scan: 1024 threads, each owns ceil(N/1024) counts.
// serial chunk sum -> shfl wave scan -> serial 16-wave scan -> write back.
__global__ __launch_bounds__(1024) void scan_offsets(const int* __restrict__ cnt,
                                                     int* __restrict__ off,
                                                     int* __restrict__ cursor) {
    const int CHUNK = (N_NODES + 1023) / 1024;  // 49
    __shared__ int wave_off[17];
    int t = threadIdx.x;
    int begin = t * CHUNK;
    int end   = min(begin + CHUNK, N_NODES);
    int sum = 0;
    for (int i = begin; i < end; ++i) sum += cnt[i];
    int lane = t & 63, wid = t >> 6;
    int incl = sum;
    for (int d = 1; d < 64; d <<= 1) {
        int u = __shfl_up(incl, d, 64);
        if (lane >= d) incl += u;
    }
    __shared__ int wave_tot[16];
    if (lane == 63) wave_tot[wid] = incl;
    __syncthreads();
    if (t == 0) {
        int run = 0;
        for (int w = 0; w < 16; ++w) { wave_off[w] = run; run += wave_tot[w]; }
        wave_off[16] = run;
    }
    __syncthreads();
    int base = wave_off[wid] + (incl - sum);  // exclusive prefix of this chunk
    int run = base;
    for (int i = begin; i < end; ++i) {
        off[i] = run; cursor[i] = run;
        run += cnt[i];
    }
    if (t == 0) off[N_NODES] = wave_off[16];
}

__global__ void scatter_edges(const int* __restrict__ src, const int* __restrict__ dst,
                              const float* __restrict__ inv_sqrt,
                              int* __restrict__ cursor,
                              int* __restrict__ srcs, float* __restrict__ wts) {
    int e = blockIdx.x * blockDim.x + threadIdx.x;
    if (e < N_EDGES) {
        int d = dst[e];
        int s = src[e];
        int pos = atomicAdd(&cursor[d], 1);
        srcs[pos] = s;
        wts[pos]  = inv_sqrt[s] * inv_sqrt[d];
    }
}

// ---- h = X @ W  (N x 64 @ 64 x 64), W staged in LDS, 8 rows per wave ----

__global__ __launch_bounds__(256) void gemm64(const float* __restrict__ X,
                                              const float* __restrict__ W,
                                              float* __restrict__ Y, int nrows) {
    __shared__ float Ws[64 * 64];
    for (int i = threadIdx.x; i < 64 * 64; i += 256) Ws[i] = W[i];
    __syncthreads();
    int wave = threadIdx.x >> 6;
    int j    = threadIdx.x & 63;
    int row0 = (blockIdx.x * 4 + wave) * 8;
    for (int r = 0; r < 8; ++r) {
        int row = row0 + r;
        if (row >= nrows) return;
        const float* xr = X + (size_t)row * DIM;
        float acc = 0.f;
#pragma unroll
        for (int k = 0; k < DIM; ++k) acc = fmaf(xr[k], Ws[k * DIM + j], acc);
        Y[(size_t)row * DIM + j] = acc;
    }
}

// ---- out[i] = relu( sum_{e:dst=i} h[src]*w_e + h[i]/deg_i + b ) ----
// one wave per node, lane = feature; gather-style, no atomics

__global__ __launch_bounds__(256) void aggregate(const float* __restrict__ H,
                                                 const int* __restrict__ off,
                                                 const int* __restrict__ srcs,
                                                 const float* __restrict__ wts,
                                                 const float* __restrict__ invdeg,
                                                 const float* __restrict__ bias,
                                                 float* __restrict__ Y) {
    int node = blockIdx.x * 4 + (threadIdx.x >> 6);
    int j    = threadIdx.x & 63;
    if (node >= N_NODES) return;
    float acc = H[(size_t)node * DIM + j] * invdeg[node];
    int s0 = off[node], s1 = off[node + 1];
    for (int k = s0; k < s1; ++k) {
        int s   = srcs[k];
        float w = wts[k];
        acc = fmaf(H[(size_t)s * DIM + j], w, acc);
    }
    acc += bias[j];
    Y[(size_t)node * DIM + j] = fmaxf(acc, 0.f);
}

// ---- fused mean-pool + FC: one block per graph, batch is sorted ----

__global__ __launch_bounds__(256) void pool_fc(const float* __restrict__ H,
                                               const int* __restrict__ batch,
                                               const float* __restrict__ fcW,
                                               const float* __restrict__ fcb,
                                               float* __restrict__ out) {
    __shared__ float part[4][64];
    __shared__ float mean[64];
    int g = blockIdx.x;
    // binary search segment [start, end) in sorted batch
    int lo = 0, hi = N_NODES;
    while (lo < hi) { int mid = (lo + hi) >> 1; if (batch[mid] < g) lo = mid + 1; else hi = mid; }
    int start = lo;
    hi = N_NODES;
    while (lo < hi) { int mid = (lo + hi) >> 1; if (batch[mid] < g + 1) lo = mid + 1; else hi = mid; }
    int end = lo;

    int wave = threadIdx.x >> 6, j = threadIdx.x & 63;
    float acc = 0.f;
    for (int n = start + wave; n < end; n += 4)
        acc += H[(size_t)n * DIM + j];
    part[wave][j] = acc;
    __syncthreads();
    if (wave == 0) {
        float s = part[0][j] + part[1][j] + part[2][j] + part[3][j];
        mean[j] = s / fmaxf((float)(end - start), 1.0f);
    }
    __syncthreads();
    if (threadIdx.x < ODIM) {
        int jj = threadIdx.x;
        float a = fcb[jj];
#pragma unroll
        for (int k = 0; k < DIM; ++k) a = fmaf(mean[k], fcW[k * ODIM + jj], a);
        out[g * ODIM + jj] = a;
    }
}

extern "C" void kernel_launch(void* const* d_in, const int* in_sizes, int n_in,
                              void* d_out, int out_size, void* d_ws, size_t ws_size,
                              hipStream_t stream) {
    const float* x    = (const float*)d_in[0];
    const float* W1   = (const float*)d_in[1];
    const float* b1   = (const float*)d_in[2];
    const float* W2   = (const float*)d_in[3];
    const float* b2   = (const float*)d_in[4];
    const float* fcW  = (const float*)d_in[5];
    const float* fcb  = (const float*)d_in[6];
    const int*   eidx = (const int*)d_in[7];
    const int*   batch= (const int*)d_in[8];
    const int* esrc = eidx;
    const int* edst = eidx + N_EDGES;
    float* out = (float*)d_out;

    char* ws = (char*)d_ws;
    size_t o = 0;
    auto alloc = [&](size_t bytes) {
        void* p = ws + o;
        o += (bytes + 255) & ~(size_t)255;
        return p;
    };
    float* bufA     = (float*)alloc((size_t)N_NODES * DIM * 4);
    float* bufB     = (float*)alloc((size_t)N_NODES * DIM * 4);
    int*   cnt      = (int*)  alloc((size_t)N_NODES * 4);
    int*   off      = (int*)  alloc((size_t)(N_NODES + 1) * 4);
    int*   cursor   = (int*)  alloc((size_t)N_NODES * 4);
    float* inv_sqrt = (float*)alloc((size_t)N_NODES * 4);
    float* invdeg   = (float*)alloc((size_t)N_NODES * 4);
    int*   srcs     = (int*)  alloc((size_t)N_EDGES * 4);
    float* wts      = (float*)alloc((size_t)N_EDGES * 4);

    hipMemsetAsync(cnt, 0, (size_t)N_NODES * 4, stream);

    count_deg<<<(N_EDGES + 255) / 256, 256, 0, stream>>>(edst, cnt);
    compute_norm<<<(N_NODES + 255) / 256, 256, 0, stream>>>(cnt, inv_sqrt, invdeg);
    scan_offsets<<<1, 1024, 0, stream>>>(cnt, off, cursor);
    scatter_edges<<<(N_EDGES + 255) / 256, 256, 0, stream>>>(esrc, edst, inv_sqrt, cursor, srcs, wts);

    gemm64<<<(N_NODES + 31) / 32, 256, 0, stream>>>(x, W1, bufA, N_NODES);
    aggregate<<<(N_NODES + 3) / 4, 256, 0, stream>>>(bufA, off, srcs, wts, invdeg, b1, bufB);
    gemm64<<<(N_NODES + 31) / 32, 256, 0, stream>>>(bufB, W2, bufA, N_NODES);
    aggregate<<<(N_NODES + 3) / 4, 256, 0, stream>>>(bufA, off, srcs, wts, invdeg, b2, bufB);

    pool_fc<<<N_GRAPHS, 256, 0, stream>>>(bufB, batch, fcW, fcb, out);
}

// Round 3
// 402.130 us; speedup vs baseline: 1.4371x; 1.2663x over previous
//
#include <hip/hip_runtime.h>

#define N_NODES 50000
#define N_EDGES 800000
#define DIM 64
#define ODIM 32
#define N_GRAPHS 512
#define SCAN_NB ((N_NODES + 255) / 256)   // 196

// ---- graph prep: counting-sort edges by dst into CSR ----

__global__ void count_deg(const int* __restrict__ dst, int* __restrict__ cnt) {
    int e = blockIdx.x * blockDim.x + threadIdx.x;
    if (e < N_EDGES) atomicAdd(&cnt[dst[e]], 1);
}

__global__ void compute_norm(const int* __restrict__ cnt,
                             float* __restrict__ inv_sqrt, float* __restrict__ invdeg) {
    int i = blockIdx.x * blockDim.x + threadIdx.x;
    if (i < N_NODES) {
        float d = (float)(cnt[i] + 1);   // self-loop
        inv_sqrt[i] = rsqrtf(d);
        invdeg[i]   = 1.0f / d;
    }
}

// ---- 3-phase exclusive scan over cnt[N_NODES] ----

__global__ __launch_bounds__(256) void scan_p1(const int* __restrict__ cnt,
                                               int* __restrict__ blocksum) {
    __shared__ int ws[4];
    int i = blockIdx.x * 256 + threadIdx.x;
    int v = (i < N_NODES) ? cnt[i] : 0;
    for (int d = 32; d > 0; d >>= 1) v += __shfl_down(v, d, 64);
    int lane = threadIdx.x & 63, wid = threadIdx.x >> 6;
    if (lane == 0) ws[wid] = v;
    __syncthreads();
    if (threadIdx.x == 0) blocksum[blockIdx.x] = ws[0] + ws[1] + ws[2] + ws[3];
}

__global__ __launch_bounds__(256) void scan_p2(const int* __restrict__ blocksum,
                                               int* __restrict__ blockbase,
                                               int* __restrict__ off) {
    __shared__ int wtot[4];
    int t = threadIdx.x;
    int v = (t < SCAN_NB) ? blocksum[t] : 0;
    int lane = t & 63, wid = t >> 6;
    int incl = v;
    for (int d = 1; d < 64; d <<= 1) {
        int u = __shfl_up(incl, d, 64);
        if (lane >= d) incl += u;
    }
    if (lane == 63) wtot[wid] = incl;
    __syncthreads();
    int base = 0;
    for (int w = 0; w < wid; ++w) base += wtot[w];
    incl += base;
    if (t < SCAN_NB) blockbase[t] = incl - v;   // exclusive
    if (t == SCAN_NB - 1) off[N_NODES] = incl;
}

__global__ __launch_bounds__(256) void scan_p3(const int* __restrict__ cnt,
                                               const int* __restrict__ blockbase,
                                               int* __restrict__ off,
                                               int* __restrict__ cursor) {
    __shared__ int wtot[4];
    int i = blockIdx.x * 256 + threadIdx.x;
    int v = (i < N_NODES) ? cnt[i] : 0;
    int lane = threadIdx.x & 63, wid = threadIdx.x >> 6;
    int incl = v;
    for (int d = 1; d < 64; d <<= 1) {
        int u = __shfl_up(incl, d, 64);
        if (lane >= d) incl += u;
    }
    if (lane == 63) wtot[wid] = incl;
    __syncthreads();
    int base = blockbase[blockIdx.x];
    for (int w = 0; w < wid; ++w) base += wtot[w];
    int excl = base + incl - v;
    if (i < N_NODES) { off[i] = excl; cursor[i] = excl; }
}

__global__ void scatter_edges(const int* __restrict__ src, const int* __restrict__ dst,
                              const float* __restrict__ inv_sqrt,
                              int* __restrict__ cursor,
                              int* __restrict__ srcs, float* __restrict__ wts) {
    int e = blockIdx.x * blockDim.x + threadIdx.x;
    if (e < N_EDGES) {
        int d = dst[e];
        int s = src[e];
        int pos = atomicAdd(&cursor[d], 1);
        srcs[pos] = s;
        wts[pos]  = inv_sqrt[s] * inv_sqrt[d];
    }
}

// ---- h = X @ W  (N x 64 @ 64 x 64), W staged in LDS, 8 rows per wave ----

__global__ __launch_bounds__(256) void gemm64(const float* __restrict__ X,
                                              const float* __restrict__ W,
                                              float* __restrict__ Y, int nrows) {
    __shared__ float Ws[64 * 64];
    for (int i = threadIdx.x; i < 64 * 64; i += 256) Ws[i] = W[i];
    __syncthreads();
    int wave = threadIdx.x >> 6;
    int j    = threadIdx.x & 63;
    int row0 = (blockIdx.x * 4 + wave) * 8;
    for (int r = 0; r < 8; ++r) {
        int row = row0 + r;
        if (row >= nrows) return;
        const float* xr = X + (size_t)row * DIM;
        float acc = 0.f;
#pragma unroll
        for (int k = 0; k < DIM; ++k) acc = fmaf(xr[k], Ws[k * DIM + j], acc);
        Y[(size_t)row * DIM + j] = acc;
    }
}

// ---- out[i] = relu( sum_{e:dst=i} h[src]*w_e + h[i]/deg_i + b ) ----
// one wave per node, lane = feature; gather-style, no atomics

__global__ __launch_bounds__(256) void aggregate(const float* __restrict__ H,
                                                 const int* __restrict__ off,
                                                 const int* __restrict__ srcs,
                                                 const float* __restrict__ wts,
                                                 const float* __restrict__ invdeg,
                                                 const float* __restrict__ bias,
                                                 float* __restrict__ Y) {
    int node = blockIdx.x * 4 + (threadIdx.x >> 6);
    int j    = threadIdx.x & 63;
    if (node >= N_NODES) return;
    float acc = H[(size_t)node * DIM + j] * invdeg[node];
    int s0 = off[node], s1 = off[node + 1];
    for (int k = s0; k < s1; ++k) {
        int s   = srcs[k];
        float w = wts[k];
        acc = fmaf(H[(size_t)s * DIM + j], w, acc);
    }
    acc += bias[j];
    Y[(size_t)node * DIM + j] = fmaxf(acc, 0.f);
}

// ---- fused mean-pool + FC: one block per graph, batch is sorted ----

__global__ __launch_bounds__(256) void pool_fc(const float* __restrict__ H,
                                               const int* __restrict__ batch,
                                               const float* __restrict__ fcW,
                                               const float* __restrict__ fcb,
                                               float* __restrict__ out) {
    __shared__ float part[4][64];
    __shared__ float mean[64];
    int g = blockIdx.x;
    int lo = 0, hi = N_NODES;
    while (lo < hi) { int mid = (lo + hi) >> 1; if (batch[mid] < g) lo = mid + 1; else hi = mid; }
    int start = lo;
    hi = N_NODES;
    while (lo < hi) { int mid = (lo + hi) >> 1; if (batch[mid] < g + 1) lo = mid + 1; else hi = mid; }
    int end = lo;

    int wave = threadIdx.x >> 6, j = threadIdx.x & 63;
    float acc = 0.f;
    for (int n = start + wave; n < end; n += 4)
        acc += H[(size_t)n * DIM + j];
    part[wave][j] = acc;
    __syncthreads();
    if (wave == 0) {
        float s = part[0][j] + part[1][j] + part[2][j] + part[3][j];
        mean[j] = s / fmaxf((float)(end - start), 1.0f);
    }
    __syncthreads();
    if (threadIdx.x < ODIM) {
        int jj = threadIdx.x;
        float a = fcb[jj];
#pragma unroll
        for (int k = 0; k < DIM; ++k) a = fmaf(mean[k], fcW[k * ODIM + jj], a);
        out[g * ODIM + jj] = a;
    }
}

extern "C" void kernel_launch(void* const* d_in, const int* in_sizes, int n_in,
                              void* d_out, int out_size, void* d_ws, size_t ws_size,
                              hipStream_t stream) {
    const float* x    = (const float*)d_in[0];
    const float* W1   = (const float*)d_in[1];
    const float* b1   = (const float*)d_in[2];
    const float* W2   = (const float*)d_in[3];
    const float* b2   = (const float*)d_in[4];
    const float* fcW  = (const float*)d_in[5];
    const float* fcb  = (const float*)d_in[6];
    const int*   eidx = (const int*)d_in[7];
    const int*   batch= (const int*)d_in[8];
    const int* esrc = eidx;
    const int* edst = eidx + N_EDGES;
    float* out = (float*)d_out;

    char* ws = (char*)d_ws;
    size_t o = 0;
    auto alloc = [&](size_t bytes) {
        void* p = ws + o;
        o += (bytes + 255) & ~(size_t)255;
        return p;
    };
    float* bufA     = (float*)alloc((size_t)N_NODES * DIM * 4);
    float* bufB     = (float*)alloc((size_t)N_NODES * DIM * 4);
    int*   cnt      = (int*)  alloc((size_t)N_NODES * 4);
    int*   off      = (int*)  alloc((size_t)(N_NODES + 1) * 4);
    int*   cursor   = (int*)  alloc((size_t)N_NODES * 4);
    float* inv_sqrt = (float*)alloc((size_t)N_NODES * 4);
    float* invdeg   = (float*)alloc((size_t)N_NODES * 4);
    int*   srcs     = (int*)  alloc((size_t)N_EDGES * 4);
    float* wts      = (float*)alloc((size_t)N_EDGES * 4);
    int*   blocksum = (int*)  alloc((size_t)SCAN_NB * 4);
    int*   blockbase= (int*)  alloc((size_t)SCAN_NB * 4);

    hipMemsetAsync(cnt, 0, (size_t)N_NODES * 4, stream);

    count_deg<<<(N_EDGES + 255) / 256, 256, 0, stream>>>(edst, cnt);
    compute_norm<<<(N_NODES + 255) / 256, 256, 0, stream>>>(cnt, inv_sqrt, invdeg);
    scan_p1<<<SCAN_NB, 256, 0, stream>>>(cnt, blocksum);
    scan_p2<<<1, 256, 0, stream>>>(blocksum, blockbase, off);
    scan_p3<<<SCAN_NB, 256, 0, stream>>>(cnt, blockbase, off, cursor);
    scatter_edges<<<(N_EDGES + 255) / 256, 256, 0, stream>>>(esrc, edst, inv_sqrt, cursor, srcs, wts);

    gemm64<<<(N_NODES + 31) / 32, 256, 0, stream>>>(x, W1, bufA, N_NODES);
    aggregate<<<(N_NODES + 3) / 4, 256, 0, stream>>>(bufA, off, srcs, wts, invdeg, b1, bufB);
    gemm64<<<(N_NODES + 31) / 32, 256, 0, stream>>>(bufB, W2, bufA, N_NODES);
    aggregate<<<(N_NODES + 3) / 4, 256, 0, stream>>>(bufA, off, srcs, wts, invdeg, b2, bufB);

    pool_fc<<<N_GRAPHS, 256, 0, stream>>>(bufB, batch, fcW, fcb, out);
}

// Round 4
// 327.683 us; speedup vs baseline: 1.7636x; 1.2272x over previous
//
#include <hip/hip_runtime.h>

#define N_NODES 50000
#define N_EDGES 800000
#define DIM 64
#define ODIM 32
#define N_GRAPHS 512
#define SCAN_NB ((N_NODES + 255) / 256)   // 196

// ---- graph prep: counting-sort edges by dst into CSR ----

__global__ void count_deg(const int* __restrict__ dst, int* __restrict__ cnt) {
    int e = blockIdx.x * blockDim.x + threadIdx.x;
    if (e < N_EDGES) atomicAdd(&cnt[dst[e]], 1);
}

__global__ void compute_norm(const int* __restrict__ cnt,
                             float* __restrict__ inv_sqrt, float* __restrict__ invdeg) {
    int i = blockIdx.x * blockDim.x + threadIdx.x;
    if (i < N_NODES) {
        float d = (float)(cnt[i] + 1);   // self-loop
        inv_sqrt[i] = rsqrtf(d);
        invdeg[i]   = 1.0f / d;
    }
}

// ---- 3-phase exclusive scan over cnt[N_NODES] ----

__global__ __launch_bounds__(256) void scan_p1(const int* __restrict__ cnt,
                                               int* __restrict__ blocksum) {
    __shared__ int ws[4];
    int i = blockIdx.x * 256 + threadIdx.x;
    int v = (i < N_NODES) ? cnt[i] : 0;
    for (int d = 32; d > 0; d >>= 1) v += __shfl_down(v, d, 64);
    int lane = threadIdx.x & 63, wid = threadIdx.x >> 6;
    if (lane == 0) ws[wid] = v;
    __syncthreads();
    if (threadIdx.x == 0) blocksum[blockIdx.x] = ws[0] + ws[1] + ws[2] + ws[3];
}

__global__ __launch_bounds__(256) void scan_p2(const int* __restrict__ blocksum,
                                               int* __restrict__ blockbase,
                                               int* __restrict__ off) {
    __shared__ int wtot[4];
    int t = threadIdx.x;
    int v = (t < SCAN_NB) ? blocksum[t] : 0;
    int lane = t & 63, wid = t >> 6;
    int incl = v;
    for (int d = 1; d < 64; d <<= 1) {
        int u = __shfl_up(incl, d, 64);
        if (lane >= d) incl += u;
    }
    if (lane == 63) wtot[wid] = incl;
    __syncthreads();
    int base = 0;
    for (int w = 0; w < wid; ++w) base += wtot[w];
    incl += base;
    if (t < SCAN_NB) blockbase[t] = incl - v;   // exclusive
    if (t == SCAN_NB - 1) off[N_NODES] = incl;
}

__global__ __launch_bounds__(256) void scan_p3(const int* __restrict__ cnt,
                                               const int* __restrict__ blockbase,
                                               int* __restrict__ off,
                                               int* __restrict__ cursor) {
    __shared__ int wtot[4];
    int i = blockIdx.x * 256 + threadIdx.x;
    int v = (i < N_NODES) ? cnt[i] : 0;
    int lane = threadIdx.x & 63, wid = threadIdx.x >> 6;
    int incl = v;
    for (int d = 1; d < 64; d <<= 1) {
        int u = __shfl_up(incl, d, 64);
        if (lane >= d) incl += u;
    }
    if (lane == 63) wtot[wid] = incl;
    __syncthreads();
    int base = blockbase[blockIdx.x];
    for (int w = 0; w < wid; ++w) base += wtot[w];
    int excl = base + incl - v;
    if (i < N_NODES) { off[i] = excl; cursor[i] = excl; }
}

__global__ void scatter_edges(const int* __restrict__ src, const int* __restrict__ dst,
                              const float* __restrict__ inv_sqrt,
                              int* __restrict__ cursor,
                              int* __restrict__ srcs, float* __restrict__ wts) {
    int e = blockIdx.x * blockDim.x + threadIdx.x;
    if (e < N_EDGES) {
        int d = dst[e];
        int s = src[e];
        int pos = atomicAdd(&cursor[d], 1);
        srcs[pos] = s;
        wts[pos]  = inv_sqrt[s] * inv_sqrt[d];
    }
}

// ---- h = X @ W  (N x 64 @ 64 x 64) ----
// W transposed into LDS, stride 68 floats (17 quads, coprime with 8 -> conflict-free b128)

__global__ __launch_bounds__(256) void gemm64(const float* __restrict__ X,
                                              const float* __restrict__ W,
                                              float* __restrict__ Y, int nrows) {
    __shared__ float Ws[64 * 68];
    for (int i = threadIdx.x; i < 64 * 64; i += 256) {
        int k = i >> 6, j = i & 63;
        Ws[j * 68 + k] = W[i];
    }
    __syncthreads();
    int wave = threadIdx.x >> 6;
    int j    = threadIdx.x & 63;
    const float* wrow = &Ws[j * 68];
    int row0 = (blockIdx.x * 4 + wave) * 8;
    for (int r = 0; r < 8; ++r) {
        int row = row0 + r;
        if (row >= nrows) return;
        const float* xr = X + (size_t)row * DIM;   // wave-uniform -> scalar loads
        float acc = 0.f;
#pragma unroll
        for (int k4 = 0; k4 < 16; ++k4) {
            float4 w4 = *(const float4*)&wrow[k4 * 4];
            acc = fmaf(xr[4 * k4 + 0], w4.x, acc);
            acc = fmaf(xr[4 * k4 + 1], w4.y, acc);
            acc = fmaf(xr[4 * k4 + 2], w4.z, acc);
            acc = fmaf(xr[4 * k4 + 3], w4.w, acc);
        }
        Y[(size_t)row * DIM + j] = acc;
    }
}

// ---- out[i] = relu( sum_{e:dst=i} h[src]*w_e + h[i]/deg_i + b ) ----
// one wave per node, lane = feature; edge loop unrolled x4 for MLP

__global__ __launch_bounds__(256) void aggregate(const float* __restrict__ H,
                                                 const int* __restrict__ off,
                                                 const int* __restrict__ srcs,
                                                 const float* __restrict__ wts,
                                                 const float* __restrict__ invdeg,
                                                 const float* __restrict__ bias,
                                                 float* __restrict__ Y) {
    int node = blockIdx.x * 4 + (threadIdx.x >> 6);
    int j    = threadIdx.x & 63;
    if (node >= N_NODES) return;
    float acc = H[(size_t)node * DIM + j] * invdeg[node];
    int s0 = off[node], s1 = off[node + 1];
    int k = s0;
    for (; k + 3 < s1; k += 4) {
        int   sA = srcs[k],   sB = srcs[k+1], sC = srcs[k+2], sD = srcs[k+3];
        float wA = wts[k],    wB = wts[k+1],  wC = wts[k+2],  wD = wts[k+3];
        float hA = H[(size_t)sA * DIM + j];
        float hB = H[(size_t)sB * DIM + j];
        float hC = H[(size_t)sC * DIM + j];
        float hD = H[(size_t)sD * DIM + j];
        acc = fmaf(hA, wA, acc);
        acc = fmaf(hB, wB, acc);
        acc = fmaf(hC, wC, acc);
        acc = fmaf(hD, wD, acc);
    }
    for (; k < s1; ++k) {
        int s   = srcs[k];
        float w = wts[k];
        acc = fmaf(H[(size_t)s * DIM + j], w, acc);
    }
    acc += bias[j];
    Y[(size_t)node * DIM + j] = fmaxf(acc, 0.f);
}

// ---- fused mean-pool + FC: one block per graph, batch is sorted ----

__global__ __launch_bounds__(256) void pool_fc(const float* __restrict__ H,
                                               const int* __restrict__ batch,
                                               const float* __restrict__ fcW,
                                               const float* __restrict__ fcb,
                                               float* __restrict__ out) {
    __shared__ float part[4][64];
    __shared__ float mean[64];
    int g = blockIdx.x;
    int lo = 0, hi = N_NODES;
    while (lo < hi) { int mid = (lo + hi) >> 1; if (batch[mid] < g) lo = mid + 1; else hi = mid; }
    int start = lo;
    hi = N_NODES;
    while (lo < hi) { int mid = (lo + hi) >> 1; if (batch[mid] < g + 1) lo = mid + 1; else hi = mid; }
    int end = lo;

    int wave = threadIdx.x >> 6, j = threadIdx.x & 63;
    float acc = 0.f;
    for (int n = start + wave; n < end; n += 4)
        acc += H[(size_t)n * DIM + j];
    part[wave][j] = acc;
    __syncthreads();
    if (wave == 0) {
        float s = part[0][j] + part[1][j] + part[2][j] + part[3][j];
        mean[j] = s / fmaxf((float)(end - start), 1.0f);
    }
    __syncthreads();
    if (threadIdx.x < ODIM) {
        int jj = threadIdx.x;
        float a = fcb[jj];
#pragma unroll
        for (int k = 0; k < DIM; ++k) a = fmaf(mean[k], fcW[k * ODIM + jj], a);
        out[g * ODIM + jj] = a;
    }
}

extern "C" void kernel_launch(void* const* d_in, const int* in_sizes, int n_in,
                              void* d_out, int out_size, void* d_ws, size_t ws_size,
                              hipStream_t stream) {
    const float* x    = (const float*)d_in[0];
    const float* W1   = (const float*)d_in[1];
    const float* b1   = (const float*)d_in[2];
    const float* W2   = (const float*)d_in[3];
    const float* b2   = (const float*)d_in[4];
    const float* fcW  = (const float*)d_in[5];
    const float* fcb  = (const float*)d_in[6];
    const int*   eidx = (const int*)d_in[7];
    const int*   batch= (const int*)d_in[8];
    const int* esrc = eidx;
    const int* edst = eidx + N_EDGES;
    float* out = (float*)d_out;

    char* ws = (char*)d_ws;
    size_t o = 0;
    auto alloc = [&](size_t bytes) {
        void* p = ws + o;
        o += (bytes + 255) & ~(size_t)255;
        return p;
    };
    float* bufA     = (float*)alloc((size_t)N_NODES * DIM * 4);
    float* bufB     = (float*)alloc((size_t)N_NODES * DIM * 4);
    int*   cnt      = (int*)  alloc((size_t)N_NODES * 4);
    int*   off      = (int*)  alloc((size_t)(N_NODES + 1) * 4);
    int*   cursor   = (int*)  alloc((size_t)N_NODES * 4);
    float* inv_sqrt = (float*)alloc((size_t)N_NODES * 4);
    float* invdeg   = (float*)alloc((size_t)N_NODES * 4);
    int*   srcs     = (int*)  alloc((size_t)N_EDGES * 4);
    float* wts      = (float*)alloc((size_t)N_EDGES * 4);
    int*   blocksum = (int*)  alloc((size_t)SCAN_NB * 4);
    int*   blockbase= (int*)  alloc((size_t)SCAN_NB * 4);

    hipMemsetAsync(cnt, 0, (size_t)N_NODES * 4, stream);

    count_deg<<<(N_EDGES + 255) / 256, 256, 0, stream>>>(edst, cnt);
    compute_norm<<<(N_NODES + 255) / 256, 256, 0, stream>>>(cnt, inv_sqrt, invdeg);
    scan_p1<<<SCAN_NB, 256, 0, stream>>>(cnt, blocksum);
    scan_p2<<<1, 256, 0, stream>>>(blocksum, blockbase, off);
    scan_p3<<<SCAN_NB, 256, 0, stream>>>(cnt, blockbase, off, cursor);
    scatter_edges<<<(N_EDGES + 255) / 256, 256, 0, stream>>>(esrc, edst, inv_sqrt, cursor, srcs, wts);

    gemm64<<<(N_NODES + 31) / 32, 256, 0, stream>>>(x, W1, bufA, N_NODES);
    aggregate<<<(N_NODES + 3) / 4, 256, 0, stream>>>(bufA, off, srcs, wts, invdeg, b1, bufB);
    gemm64<<<(N_NODES + 31) / 32, 256, 0, stream>>>(bufB, W2, bufA, N_NODES);
    aggregate<<<(N_NODES + 3) / 4, 256, 0, stream>>>(bufA, off, srcs, wts, invdeg, b2, bufB);

    pool_fc<<<N_GRAPHS, 256, 0, stream>>>(bufB, batch, fcW, fcb, out);
}

// Round 5
// 314.932 us; speedup vs baseline: 1.8350x; 1.0405x over previous
//
#include <hip/hip_runtime.h>

#define N_NODES 50000
#define N_EDGES 800000
#define DIM 64
#define ODIM 32
#define N_GRAPHS 512
#define SCAN_NB ((N_NODES + 255) / 256)   // 196

// ---- graph prep: counting-sort edges by dst into CSR ----

__global__ void count_deg(const int* __restrict__ dst, int* __restrict__ cnt) {
    int e = blockIdx.x * blockDim.x + threadIdx.x;
    if (e < N_EDGES) atomicAdd(&cnt[__builtin_nontemporal_load(&dst[e])], 1);
}

__global__ void compute_norm(const int* __restrict__ cnt,
                             float* __restrict__ inv_sqrt, float* __restrict__ invdeg) {
    int i = blockIdx.x * blockDim.x + threadIdx.x;
    if (i < N_NODES) {
        float d = (float)(cnt[i] + 1);   // self-loop
        inv_sqrt[i] = rsqrtf(d);
        invdeg[i]   = 1.0f / d;
    }
}

// ---- 3-phase exclusive scan over cnt[N_NODES] ----

__global__ __launch_bounds__(256) void scan_p1(const int* __restrict__ cnt,
                                               int* __restrict__ blocksum) {
    __shared__ int ws[4];
    int i = blockIdx.x * 256 + threadIdx.x;
    int v = (i < N_NODES) ? cnt[i] : 0;
    for (int d = 32; d > 0; d >>= 1) v += __shfl_down(v, d, 64);
    int lane = threadIdx.x & 63, wid = threadIdx.x >> 6;
    if (lane == 0) ws[wid] = v;
    __syncthreads();
    if (threadIdx.x == 0) blocksum[blockIdx.x] = ws[0] + ws[1] + ws[2] + ws[3];
}

__global__ __launch_bounds__(256) void scan_p2(const int* __restrict__ blocksum,
                                               int* __restrict__ blockbase,
                                               int* __restrict__ off) {
    __shared__ int wtot[4];
    int t = threadIdx.x;
    int v = (t < SCAN_NB) ? blocksum[t] : 0;
    int lane = t & 63, wid = t >> 6;
    int incl = v;
    for (int d = 1; d < 64; d <<= 1) {
        int u = __shfl_up(incl, d, 64);
        if (lane >= d) incl += u;
    }
    if (lane == 63) wtot[wid] = incl;
    __syncthreads();
    int base = 0;
    for (int w = 0; w < wid; ++w) base += wtot[w];
    incl += base;
    if (t < SCAN_NB) blockbase[t] = incl - v;   // exclusive
    if (t == SCAN_NB - 1) off[N_NODES] = incl;
}

__global__ __launch_bounds__(256) void scan_p3(const int* __restrict__ cnt,
                                               const int* __restrict__ blockbase,
                                               int* __restrict__ off,
                                               int* __restrict__ cursor) {
    __shared__ int wtot[4];
    int i = blockIdx.x * 256 + threadIdx.x;
    int v = (i < N_NODES) ? cnt[i] : 0;
    int lane = threadIdx.x & 63, wid = threadIdx.x >> 6;
    int incl = v;
    for (int d = 1; d < 64; d <<= 1) {
        int u = __shfl_up(incl, d, 64);
        if (lane >= d) incl += u;
    }
    if (lane == 63) wtot[wid] = incl;
    __syncthreads();
    int base = blockbase[blockIdx.x];
    for (int w = 0; w < wid; ++w) base += wtot[w];
    int excl = base + incl - v;
    if (i < N_NODES) { off[i] = excl; cursor[i] = excl; }
}

// packed edge record: {src, weight-as-int-bits} -> single 8B store
__global__ void scatter_edges(const int* __restrict__ src, const int* __restrict__ dst,
                              const float* __restrict__ inv_sqrt,
                              int* __restrict__ cursor,
                              int2* __restrict__ edges) {
    int e = blockIdx.x * blockDim.x + threadIdx.x;
    if (e < N_EDGES) {
        int d = __builtin_nontemporal_load(&dst[e]);
        int s = __builtin_nontemporal_load(&src[e]);
        int pos = atomicAdd(&cursor[d], 1);
        float w = inv_sqrt[s] * inv_sqrt[d];
        edges[pos] = make_int2(s, __float_as_int(w));
    }
}

// ---- h = X @ W  (N x 64 @ 64 x 64) ----
// W transposed into LDS, stride 68 floats (17 quads, coprime with 8 -> conflict-free b128)

__global__ __launch_bounds__(256) void gemm64(const float* __restrict__ X,
                                              const float* __restrict__ W,
                                              float* __restrict__ Y, int nrows) {
    __shared__ float Ws[64 * 68];
    for (int i = threadIdx.x; i < 64 * 64; i += 256) {
        int k = i >> 6, j = i & 63;
        Ws[j * 68 + k] = W[i];
    }
    __syncthreads();
    int wave = threadIdx.x >> 6;
    int j    = threadIdx.x & 63;
    const float* wrow = &Ws[j * 68];
    int row0 = (blockIdx.x * 4 + wave) * 8;
    for (int r = 0; r < 8; ++r) {
        int row = row0 + r;
        if (row >= nrows) return;
        const float* xr = X + (size_t)row * DIM;   // wave-uniform -> scalar loads
        float acc = 0.f;
#pragma unroll
        for (int k4 = 0; k4 < 16; ++k4) {
            float4 w4 = *(const float4*)&wrow[k4 * 4];
            acc = fmaf(xr[4 * k4 + 0], w4.x, acc);
            acc = fmaf(xr[4 * k4 + 1], w4.y, acc);
            acc = fmaf(xr[4 * k4 + 2], w4.z, acc);
            acc = fmaf(xr[4 * k4 + 3], w4.w, acc);
        }
        Y[(size_t)row * DIM + j] = acc;
    }
}

// ---- out[i] = relu( sum_{e:dst=i} h[src]*w_e + h[i]/deg_i + b ) ----
// one wave per node, lane = feature; packed int2 edges, unroll x8

__global__ __launch_bounds__(256) void aggregate(const float* __restrict__ H,
                                                 const int* __restrict__ off,
                                                 const int2* __restrict__ edges,
                                                 const float* __restrict__ invdeg,
                                                 const float* __restrict__ bias,
                                                 float* __restrict__ Y) {
    int node = blockIdx.x * 4 + (threadIdx.x >> 6);
    int j    = threadIdx.x & 63;
    if (node >= N_NODES) return;
    float acc = H[(size_t)node * DIM + j] * invdeg[node];
    int s0 = off[node], s1 = off[node + 1];
    int k = s0;
    for (; k + 7 < s1; k += 8) {
        int2 eA = edges[k],   eB = edges[k+1], eC = edges[k+2], eD = edges[k+3];
        int2 eE = edges[k+4], eF = edges[k+5], eG = edges[k+6], eH = edges[k+7];
        float hA = H[(size_t)eA.x * DIM + j];
        float hB = H[(size_t)eB.x * DIM + j];
        float hC = H[(size_t)eC.x * DIM + j];
        float hD = H[(size_t)eD.x * DIM + j];
        float hE = H[(size_t)eE.x * DIM + j];
        float hF = H[(size_t)eF.x * DIM + j];
        float hG = H[(size_t)eG.x * DIM + j];
        float hH = H[(size_t)eH.x * DIM + j];
        acc = fmaf(hA, __int_as_float(eA.y), acc);
        acc = fmaf(hB, __int_as_float(eB.y), acc);
        acc = fmaf(hC, __int_as_float(eC.y), acc);
        acc = fmaf(hD, __int_as_float(eD.y), acc);
        acc = fmaf(hE, __int_as_float(eE.y), acc);
        acc = fmaf(hF, __int_as_float(eF.y), acc);
        acc = fmaf(hG, __int_as_float(eG.y), acc);
        acc = fmaf(hH, __int_as_float(eH.y), acc);
    }
    for (; k + 3 < s1; k += 4) {
        int2 eA = edges[k], eB = edges[k+1], eC = edges[k+2], eD = edges[k+3];
        float hA = H[(size_t)eA.x * DIM + j];
        float hB = H[(size_t)eB.x * DIM + j];
        float hC = H[(size_t)eC.x * DIM + j];
        float hD = H[(size_t)eD.x * DIM + j];
        acc = fmaf(hA, __int_as_float(eA.y), acc);
        acc = fmaf(hB, __int_as_float(eB.y), acc);
        acc = fmaf(hC, __int_as_float(eC.y), acc);
        acc = fmaf(hD, __int_as_float(eD.y), acc);
    }
    for (; k < s1; ++k) {
        int2 eA = edges[k];
        acc = fmaf(H[(size_t)eA.x * DIM + j], __int_as_float(eA.y), acc);
    }
    acc += bias[j];
    Y[(size_t)node * DIM + j] = fmaxf(acc, 0.f);
}

// ---- fused mean-pool + FC: one block per graph, batch is sorted ----

__global__ __launch_bounds__(256) void pool_fc(const float* __restrict__ H,
                                               const int* __restrict__ batch,
                                               const float* __restrict__ fcW,
                                               const float* __restrict__ fcb,
                                               float* __restrict__ out) {
    __shared__ float part[4][64];
    __shared__ float mean[64];
    int g = blockIdx.x;
    int lo = 0, hi = N_NODES;
    while (lo < hi) { int mid = (lo + hi) >> 1; if (batch[mid] < g) lo = mid + 1; else hi = mid; }
    int start = lo;
    hi = N_NODES;
    while (lo < hi) { int mid = (lo + hi) >> 1; if (batch[mid] < g + 1) lo = mid + 1; else hi = mid; }
    int end = lo;

    int wave = threadIdx.x >> 6, j = threadIdx.x & 63;
    float acc = 0.f;
    for (int n = start + wave; n < end; n += 4)
        acc += H[(size_t)n * DIM + j];
    part[wave][j] = acc;
    __syncthreads();
    if (wave == 0) {
        float s = part[0][j] + part[1][j] + part[2][j] + part[3][j];
        mean[j] = s / fmaxf((float)(end - start), 1.0f);
    }
    __syncthreads();
    if (threadIdx.x < ODIM) {
        int jj = threadIdx.x;
        float a = fcb[jj];
#pragma unroll
        for (int k = 0; k < DIM; ++k) a = fmaf(mean[k], fcW[k * ODIM + jj], a);
        out[g * ODIM + jj] = a;
    }
}

extern "C" void kernel_launch(void* const* d_in, const int* in_sizes, int n_in,
                              void* d_out, int out_size, void* d_ws, size_t ws_size,
                              hipStream_t stream) {
    const float* x    = (const float*)d_in[0];
    const float* W1   = (const float*)d_in[1];
    const float* b1   = (const float*)d_in[2];
    const float* W2   = (const float*)d_in[3];
    const float* b2   = (const float*)d_in[4];
    const float* fcW  = (const float*)d_in[5];
    const float* fcb  = (const float*)d_in[6];
    const int*   eidx = (const int*)d_in[7];
    const int*   batch= (const int*)d_in[8];
    const int* esrc = eidx;
    const int* edst = eidx + N_EDGES;
    float* out = (float*)d_out;

    char* ws = (char*)d_ws;
    size_t o = 0;
    auto alloc = [&](size_t bytes) {
        void* p = ws + o;
        o += (bytes + 255) & ~(size_t)255;
        return p;
    };
    float* bufA     = (float*)alloc((size_t)N_NODES * DIM * 4);
    float* bufB     = (float*)alloc((size_t)N_NODES * DIM * 4);
    int*   cnt      = (int*)  alloc((size_t)N_NODES * 4);
    int*   off      = (int*)  alloc((size_t)(N_NODES + 1) * 4);
    int*   cursor   = (int*)  alloc((size_t)N_NODES * 4);
    float* inv_sqrt = (float*)alloc((size_t)N_NODES * 4);
    float* invdeg   = (float*)alloc((size_t)N_NODES * 4);
    int2*  edges    = (int2*) alloc((size_t)N_EDGES * 8);
    int*   blocksum = (int*)  alloc((size_t)SCAN_NB * 4);
    int*   blockbase= (int*)  alloc((size_t)SCAN_NB * 4);

    hipMemsetAsync(cnt, 0, (size_t)N_NODES * 4, stream);

    count_deg<<<(N_EDGES + 255) / 256, 256, 0, stream>>>(edst, cnt);
    compute_norm<<<(N_NODES + 255) / 256, 256, 0, stream>>>(cnt, inv_sqrt, invdeg);
    scan_p1<<<SCAN_NB, 256, 0, stream>>>(cnt, blocksum);
    scan_p2<<<1, 256, 0, stream>>>(blocksum, blockbase, off);
    scan_p3<<<SCAN_NB, 256, 0, stream>>>(cnt, blockbase, off, cursor);
    scatter_edges<<<(N_EDGES + 255) / 256, 256, 0, stream>>>(esrc, edst, inv_sqrt, cursor, edges);

    gemm64<<<(N_NODES + 31) / 32, 256, 0, stream>>>(x, W1, bufA, N_NODES);
    aggregate<<<(N_NODES + 3) / 4, 256, 0, stream>>>(bufA, off, edges, invdeg, b1, bufB);
    gemm64<<<(N_NODES + 31) / 32, 256, 0, stream>>>(bufB, W2, bufA, N_NODES);
    aggregate<<<(N_NODES + 3) / 4, 256, 0, stream>>>(bufA, off, edges, invdeg, b2, bufB);

    pool_fc<<<N_GRAPHS, 256, 0, stream>>>(bufB, batch, fcW, fcb, out);
}

// Round 6
// 308.528 us; speedup vs baseline: 1.8731x; 1.0208x over previous
//
#include <hip/hip_runtime.h>

#define N_NODES 50000
#define N_EDGES 800000
#define DIM 64
#define ODIM 32
#define N_GRAPHS 512
#define SCAN_NB ((N_NODES + 255) / 256)   // 196
#define NXCD 8
#define DST_RANGE ((N_NODES + NXCD - 1) / NXCD)   // 6250

// ---- graph prep: counting-sort edges by dst into CSR ----

__global__ void count_deg(const int* __restrict__ dst, int* __restrict__ cnt) {
    int e = blockIdx.x * blockDim.x + threadIdx.x;
    if (e < N_EDGES) atomicAdd(&cnt[__builtin_nontemporal_load(&dst[e])], 1);
}

__global__ void compute_norm(const int* __restrict__ cnt,
                             float* __restrict__ inv_sqrt, float* __restrict__ invdeg) {
    int i = blockIdx.x * blockDim.x + threadIdx.x;
    if (i < N_NODES) {
        float d = (float)(cnt[i] + 1);   // self-loop
        inv_sqrt[i] = rsqrtf(d);
        invdeg[i]   = 1.0f / d;
    }
}

// ---- 3-phase exclusive scan over cnt[N_NODES] ----

__global__ __launch_bounds__(256) void scan_p1(const int* __restrict__ cnt,
                                               int* __restrict__ blocksum) {
    __shared__ int ws[4];
    int i = blockIdx.x * 256 + threadIdx.x;
    int v = (i < N_NODES) ? cnt[i] : 0;
    for (int d = 32; d > 0; d >>= 1) v += __shfl_down(v, d, 64);
    int lane = threadIdx.x & 63, wid = threadIdx.x >> 6;
    if (lane == 0) ws[wid] = v;
    __syncthreads();
    if (threadIdx.x == 0) blocksum[blockIdx.x] = ws[0] + ws[1] + ws[2] + ws[3];
}

__global__ __launch_bounds__(256) void scan_p2(const int* __restrict__ blocksum,
                                               int* __restrict__ blockbase,
                                               int* __restrict__ off) {
    __shared__ int wtot[4];
    int t = threadIdx.x;
    int v = (t < SCAN_NB) ? blocksum[t] : 0;
    int lane = t & 63, wid = t >> 6;
    int incl = v;
    for (int d = 1; d < 64; d <<= 1) {
        int u = __shfl_up(incl, d, 64);
        if (lane >= d) incl += u;
    }
    if (lane == 63) wtot[wid] = incl;
    __syncthreads();
    int base = 0;
    for (int w = 0; w < wid; ++w) base += wtot[w];
    incl += base;
    if (t < SCAN_NB) blockbase[t] = incl - v;   // exclusive
    if (t == SCAN_NB - 1) off[N_NODES] = incl;
}

__global__ __launch_bounds__(256) void scan_p3(const int* __restrict__ cnt,
                                               const int* __restrict__ blockbase,
                                               int* __restrict__ off,
                                               int* __restrict__ cursor) {
    __shared__ int wtot[4];
    int i = blockIdx.x * 256 + threadIdx.x;
    int v = (i < N_NODES) ? cnt[i] : 0;
    int lane = threadIdx.x & 63, wid = threadIdx.x >> 6;
    int incl = v;
    for (int d = 1; d < 64; d <<= 1) {
        int u = __shfl_up(incl, d, 64);
        if (lane >= d) incl += u;
    }
    if (lane == 63) wtot[wid] = incl;
    __syncthreads();
    int base = blockbase[blockIdx.x];
    for (int w = 0; w < wid; ++w) base += wtot[w];
    int excl = base + incl - v;
    if (i < N_NODES) { off[i] = excl; cursor[i] = excl; }
}

// XCD-partitioned scatter: block = (chunk, range). Only edges with dst in
// [range*DST_RANGE, (range+1)*DST_RANGE) are kept; with blockIdx%8 -> XCD
// round-robin, each CSR region is written by a single XCD's L2.
__global__ void scatter_edges(const int* __restrict__ src, const int* __restrict__ dst,
                              const float* __restrict__ inv_sqrt,
                              int* __restrict__ cursor,
                              int2* __restrict__ edges) {
    int chunk = blockIdx.x >> 3;
    int range = blockIdx.x & 7;
    int e = chunk * 256 + threadIdx.x;
    if (e >= N_EDGES) return;
    int d = dst[e];
    int lo = range * DST_RANGE;
    if ((unsigned)(d - lo) < (unsigned)DST_RANGE) {
        int s = src[e];
        int pos = atomicAdd(&cursor[d], 1);
        float w = inv_sqrt[s] * inv_sqrt[d];
        edges[pos] = make_int2(s, __float_as_int(w));
    }
}

// ---- h = X @ W  (N x 64 @ 64 x 64) ----
// W transposed into LDS, stride 68 floats (17 quads, coprime with 8 -> conflict-free b128)

__global__ __launch_bounds__(256) void gemm64(const float* __restrict__ X,
                                              const float* __restrict__ W,
                                              float* __restrict__ Y, int nrows) {
    __shared__ float Ws[64 * 68];
    for (int i = threadIdx.x; i < 64 * 64; i += 256) {
        int k = i >> 6, j = i & 63;
        Ws[j * 68 + k] = W[i];
    }
    __syncthreads();
    int wave = threadIdx.x >> 6;
    int j    = threadIdx.x & 63;
    const float* wrow = &Ws[j * 68];
    int row0 = (blockIdx.x * 4 + wave) * 8;
    for (int r = 0; r < 8; ++r) {
        int row = row0 + r;
        if (row >= nrows) return;
        const float* xr = X + (size_t)row * DIM;   // wave-uniform -> scalar loads
        float acc = 0.f;
#pragma unroll
        for (int k4 = 0; k4 < 16; ++k4) {
            float4 w4 = *(const float4*)&wrow[k4 * 4];
            acc = fmaf(xr[4 * k4 + 0], w4.x, acc);
            acc = fmaf(xr[4 * k4 + 1], w4.y, acc);
            acc = fmaf(xr[4 * k4 + 2], w4.z, acc);
            acc = fmaf(xr[4 * k4 + 3], w4.w, acc);
        }
        Y[(size_t)row * DIM + j] = acc;
    }
}

// ---- out[i] = relu( sum_{e:dst=i} h[src]*w_e + h[i]/deg_i + b ) ----
// one wave per node, lane = feature; packed int2 edges, unroll x8

__global__ __launch_bounds__(256) void aggregate(const float* __restrict__ H,
                                                 const int* __restrict__ off,
                                                 const int2* __restrict__ edges,
                                                 const float* __restrict__ invdeg,
                                                 const float* __restrict__ bias,
                                                 float* __restrict__ Y) {
    int node = blockIdx.x * 4 + (threadIdx.x >> 6);
    int j    = threadIdx.x & 63;
    if (node >= N_NODES) return;
    float acc = H[(size_t)node * DIM + j] * invdeg[node];
    int s0 = off[node], s1 = off[node + 1];
    int k = s0;
    for (; k + 7 < s1; k += 8) {
        int2 eA = edges[k],   eB = edges[k+1], eC = edges[k+2], eD = edges[k+3];
        int2 eE = edges[k+4], eF = edges[k+5], eG = edges[k+6], eH = edges[k+7];
        float hA = H[(size_t)eA.x * DIM + j];
        float hB = H[(size_t)eB.x * DIM + j];
        float hC = H[(size_t)eC.x * DIM + j];
        float hD = H[(size_t)eD.x * DIM + j];
        float hE = H[(size_t)eE.x * DIM + j];
        float hF = H[(size_t)eF.x * DIM + j];
        float hG = H[(size_t)eG.x * DIM + j];
        float hH = H[(size_t)eH.x * DIM + j];
        acc = fmaf(hA, __int_as_float(eA.y), acc);
        acc = fmaf(hB, __int_as_float(eB.y), acc);
        acc = fmaf(hC, __int_as_float(eC.y), acc);
        acc = fmaf(hD, __int_as_float(eD.y), acc);
        acc = fmaf(hE, __int_as_float(eE.y), acc);
        acc = fmaf(hF, __int_as_float(eF.y), acc);
        acc = fmaf(hG, __int_as_float(eG.y), acc);
        acc = fmaf(hH, __int_as_float(eH.y), acc);
    }
    for (; k + 3 < s1; k += 4) {
        int2 eA = edges[k], eB = edges[k+1], eC = edges[k+2], eD = edges[k+3];
        float hA = H[(size_t)eA.x * DIM + j];
        float hB = H[(size_t)eB.x * DIM + j];
        float hC = H[(size_t)eC.x * DIM + j];
        float hD = H[(size_t)eD.x * DIM + j];
        acc = fmaf(hA, __int_as_float(eA.y), acc);
        acc = fmaf(hB, __int_as_float(eB.y), acc);
        acc = fmaf(hC, __int_as_float(eC.y), acc);
        acc = fmaf(hD, __int_as_float(eD.y), acc);
    }
    for (; k < s1; ++k) {
        int2 eA = edges[k];
        acc = fmaf(H[(size_t)eA.x * DIM + j], __int_as_float(eA.y), acc);
    }
    acc += bias[j];
    Y[(size_t)node * DIM + j] = fmaxf(acc, 0.f);
}

// ---- fused mean-pool + FC: one block per graph, batch is sorted ----

__global__ __launch_bounds__(256) void pool_fc(const float* __restrict__ H,
                                               const int* __restrict__ batch,
                                               const float* __restrict__ fcW,
                                               const float* __restrict__ fcb,
                                               float* __restrict__ out) {
    __shared__ float part[4][64];
    __shared__ float mean[64];
    int g = blockIdx.x;
    int lo = 0, hi = N_NODES;
    while (lo < hi) { int mid = (lo + hi) >> 1; if (batch[mid] < g) lo = mid + 1; else hi = mid; }
    int start = lo;
    hi = N_NODES;
    while (lo < hi) { int mid = (lo + hi) >> 1; if (batch[mid] < g + 1) lo = mid + 1; else hi = mid; }
    int end = lo;

    int wave = threadIdx.x >> 6, j = threadIdx.x & 63;
    float acc = 0.f;
    for (int n = start + wave; n < end; n += 4)
        acc += H[(size_t)n * DIM + j];
    part[wave][j] = acc;
    __syncthreads();
    if (wave == 0) {
        float s = part[0][j] + part[1][j] + part[2][j] + part[3][j];
        mean[j] = s / fmaxf((float)(end - start), 1.0f);
    }
    __syncthreads();
    if (threadIdx.x < ODIM) {
        int jj = threadIdx.x;
        float a = fcb[jj];
#pragma unroll
        for (int k = 0; k < DIM; ++k) a = fmaf(mean[k], fcW[k * ODIM + jj], a);
        out[g * ODIM + jj] = a;
    }
}

extern "C" void kernel_launch(void* const* d_in, const int* in_sizes, int n_in,
                              void* d_out, int out_size, void* d_ws, size_t ws_size,
                              hipStream_t stream) {
    const float* x    = (const float*)d_in[0];
    const float* W1   = (const float*)d_in[1];
    const float* b1   = (const float*)d_in[2];
    const float* W2   = (const float*)d_in[3];
    const float* b2   = (const float*)d_in[4];
    const float* fcW  = (const float*)d_in[5];
    const float* fcb  = (const float*)d_in[6];
    const int*   eidx = (const int*)d_in[7];
    const int*   batch= (const int*)d_in[8];
    const int* esrc = eidx;
    const int* edst = eidx + N_EDGES;
    float* out = (float*)d_out;

    char* ws = (char*)d_ws;
    size_t o = 0;
    auto alloc = [&](size_t bytes) {
        void* p = ws + o;
        o += (bytes + 255) & ~(size_t)255;
        return p;
    };
    float* bufA     = (float*)alloc((size_t)N_NODES * DIM * 4);
    float* bufB     = (float*)alloc((size_t)N_NODES * DIM * 4);
    int*   cnt      = (int*)  alloc((size_t)N_NODES * 4);
    int*   off      = (int*)  alloc((size_t)(N_NODES + 1) * 4);
    int*   cursor   = (int*)  alloc((size_t)N_NODES * 4);
    float* inv_sqrt = (float*)alloc((size_t)N_NODES * 4);
    float* invdeg   = (float*)alloc((size_t)N_NODES * 4);
    int2*  edges    = (int2*) alloc((size_t)N_EDGES * 8);
    int*   blocksum = (int*)  alloc((size_t)SCAN_NB * 4);
    int*   blockbase= (int*)  alloc((size_t)SCAN_NB * 4);

    hipMemsetAsync(cnt, 0, (size_t)N_NODES * 4, stream);

    count_deg<<<(N_EDGES + 255) / 256, 256, 0, stream>>>(edst, cnt);
    compute_norm<<<(N_NODES + 255) / 256, 256, 0, stream>>>(cnt, inv_sqrt, invdeg);
    scan_p1<<<SCAN_NB, 256, 0, stream>>>(cnt, blocksum);
    scan_p2<<<1, 256, 0, stream>>>(blocksum, blockbase, off);
    scan_p3<<<SCAN_NB, 256, 0, stream>>>(cnt, blockbase, off, cursor);
    scatter_edges<<<((N_EDGES + 255) / 256) * NXCD, 256, 0, stream>>>(esrc, edst, inv_sqrt, cursor, edges);

    gemm64<<<(N_NODES + 31) / 32, 256, 0, stream>>>(x, W1, bufA, N_NODES);
    aggregate<<<(N_NODES + 3) / 4, 256, 0, stream>>>(bufA, off, edges, invdeg, b1, bufB);
    gemm64<<<(N_NODES + 31) / 32, 256, 0, stream>>>(bufB, W2, bufA, N_NODES);
    aggregate<<<(N_NODES + 3) / 4, 256, 0, stream>>>(bufA, off, edges, invdeg, b2, bufB);

    pool_fc<<<N_GRAPHS, 256, 0, stream>>>(bufB, batch, fcW, fcb, out);
}

// Round 7
// 303.113 us; speedup vs baseline: 1.9065x; 1.0179x over previous
//
#include <hip/hip_runtime.h>
#include <hip/hip_bf16.h>

#define N_NODES 50000
#define N_EDGES 800000
#define DIM 64
#define ODIM 32
#define N_GRAPHS 512
#define SCAN_NB ((N_NODES + 255) / 256)   // 196
#define NXCD 8
#define DST_RANGE ((N_NODES + NXCD - 1) / NXCD)   // 6250

// ---- graph prep: counting-sort edges by dst into CSR ----

__global__ void count_deg(const int* __restrict__ dst, int* __restrict__ cnt) {
    int e = blockIdx.x * blockDim.x + threadIdx.x;
    if (e < N_EDGES) atomicAdd(&cnt[__builtin_nontemporal_load(&dst[e])], 1);
}

// ---- 3-phase exclusive scan over cnt[N_NODES]; p3 also emits norm terms ----

__global__ __launch_bounds__(256) void scan_p1(const int* __restrict__ cnt,
                                               int* __restrict__ blocksum) {
    __shared__ int ws[4];
    int i = blockIdx.x * 256 + threadIdx.x;
    int v = (i < N_NODES) ? cnt[i] : 0;
    for (int d = 32; d > 0; d >>= 1) v += __shfl_down(v, d, 64);
    int lane = threadIdx.x & 63, wid = threadIdx.x >> 6;
    if (lane == 0) ws[wid] = v;
    __syncthreads();
    if (threadIdx.x == 0) blocksum[blockIdx.x] = ws[0] + ws[1] + ws[2] + ws[3];
}

__global__ __launch_bounds__(256) void scan_p2(const int* __restrict__ blocksum,
                                               int* __restrict__ blockbase,
                                               int* __restrict__ off) {
    __shared__ int wtot[4];
    int t = threadIdx.x;
    int v = (t < SCAN_NB) ? blocksum[t] : 0;
    int lane = t & 63, wid = t >> 6;
    int incl = v;
    for (int d = 1; d < 64; d <<= 1) {
        int u = __shfl_up(incl, d, 64);
        if (lane >= d) incl += u;
    }
    if (lane == 63) wtot[wid] = incl;
    __syncthreads();
    int base = 0;
    for (int w = 0; w < wid; ++w) base += wtot[w];
    incl += base;
    if (t < SCAN_NB) blockbase[t] = incl - v;   // exclusive
    if (t == SCAN_NB - 1) off[N_NODES] = incl;
}

__global__ __launch_bounds__(256) void scan_p3(const int* __restrict__ cnt,
                                               const int* __restrict__ blockbase,
                                               int* __restrict__ off,
                                               int* __restrict__ cursor,
                                               float* __restrict__ inv_sqrt,
                                               float* __restrict__ invdeg) {
    __shared__ int wtot[4];
    int i = blockIdx.x * 256 + threadIdx.x;
    int v = (i < N_NODES) ? cnt[i] : 0;
    int lane = threadIdx.x & 63, wid = threadIdx.x >> 6;
    int incl = v;
    for (int d = 1; d < 64; d <<= 1) {
        int u = __shfl_up(incl, d, 64);
        if (lane >= d) incl += u;
    }
    if (lane == 63) wtot[wid] = incl;
    __syncthreads();
    int base = blockbase[blockIdx.x];
    for (int w = 0; w < wid; ++w) base += wtot[w];
    int excl = base + incl - v;
    if (i < N_NODES) {
        off[i] = excl; cursor[i] = excl;
        float d = (float)(v + 1);   // self-loop
        inv_sqrt[i] = rsqrtf(d);
        invdeg[i]   = 1.0f / d;
    }
}

// XCD-partitioned scatter: block = (chunk, range). Only edges with dst in
// [range*DST_RANGE, (range+1)*DST_RANGE) are kept; with blockIdx%8 -> XCD
// round-robin, each CSR region is written by a single XCD's L2.
__global__ void scatter_edges(const int* __restrict__ src, const int* __restrict__ dst,
                              const float* __restrict__ inv_sqrt,
                              int* __restrict__ cursor,
                              int2* __restrict__ edges) {
    int chunk = blockIdx.x >> 3;
    int range = blockIdx.x & 7;
    int e = chunk * 256 + threadIdx.x;
    if (e >= N_EDGES) return;
    int d = dst[e];
    int lo = range * DST_RANGE;
    if ((unsigned)(d - lo) < (unsigned)DST_RANGE) {
        int s = src[e];
        int pos = atomicAdd(&cursor[d], 1);
        float w = inv_sqrt[s] * inv_sqrt[d];
        edges[pos] = make_int2(s, __float_as_int(w));
    }
}

// ---- h = X @ W  (N x 64 @ 64 x 64); writes fp32 Y and bf16 copy Ybf ----
// W transposed into LDS, stride 68 floats (17 quads, coprime with 8 -> conflict-free b128)

__global__ __launch_bounds__(256) void gemm64(const float* __restrict__ X,
                                              const float* __restrict__ W,
                                              float* __restrict__ Y,
                                              __hip_bfloat16* __restrict__ Ybf,
                                              int nrows) {
    __shared__ float Ws[64 * 68];
    for (int i = threadIdx.x; i < 64 * 64; i += 256) {
        int k = i >> 6, j = i & 63;
        Ws[j * 68 + k] = W[i];
    }
    __syncthreads();
    int wave = threadIdx.x >> 6;
    int j    = threadIdx.x & 63;
    const float* wrow = &Ws[j * 68];
    int row0 = (blockIdx.x * 4 + wave) * 8;
    for (int r = 0; r < 8; ++r) {
        int row = row0 + r;
        if (row >= nrows) return;
        const float* xr = X + (size_t)row * DIM;   // wave-uniform -> scalar loads
        float acc = 0.f;
#pragma unroll
        for (int k4 = 0; k4 < 16; ++k4) {
            float4 w4 = *(const float4*)&wrow[k4 * 4];
            acc = fmaf(xr[4 * k4 + 0], w4.x, acc);
            acc = fmaf(xr[4 * k4 + 1], w4.y, acc);
            acc = fmaf(xr[4 * k4 + 2], w4.z, acc);
            acc = fmaf(xr[4 * k4 + 3], w4.w, acc);
        }
        Y[(size_t)row * DIM + j]   = acc;
        Ybf[(size_t)row * DIM + j] = __float2bfloat16(acc);
    }
}

// ---- out[i] = relu( sum_{e:dst=i} hbf[src]*w_e + h[i]/deg_i + b ) ----
// one wave per node, lane = feature; neighbor gather from bf16 copy (1 line/row)

__global__ __launch_bounds__(256) void aggregate(const float* __restrict__ H,
                                                 const __hip_bfloat16* __restrict__ Hbf,
                                                 const int* __restrict__ off,
                                                 const int2* __restrict__ edges,
                                                 const float* __restrict__ invdeg,
                                                 const float* __restrict__ bias,
                                                 float* __restrict__ Y) {
    int node = blockIdx.x * 4 + (threadIdx.x >> 6);
    int j    = threadIdx.x & 63;
    if (node >= N_NODES) return;
    float acc = H[(size_t)node * DIM + j] * invdeg[node];
    int s0 = off[node], s1 = off[node + 1];
    int k = s0;
    for (; k + 7 < s1; k += 8) {
        int2 eA = edges[k],   eB = edges[k+1], eC = edges[k+2], eD = edges[k+3];
        int2 eE = edges[k+4], eF = edges[k+5], eG = edges[k+6], eH = edges[k+7];
        float hA = __bfloat162float(Hbf[(size_t)eA.x * DIM + j]);
        float hB = __bfloat162float(Hbf[(size_t)eB.x * DIM + j]);
        float hC = __bfloat162float(Hbf[(size_t)eC.x * DIM + j]);
        float hD = __bfloat162float(Hbf[(size_t)eD.x * DIM + j]);
        float hE = __bfloat162float(Hbf[(size_t)eE.x * DIM + j]);
        float hF = __bfloat162float(Hbf[(size_t)eF.x * DIM + j]);
        float hG = __bfloat162float(Hbf[(size_t)eG.x * DIM + j]);
        float hH = __bfloat162float(Hbf[(size_t)eH.x * DIM + j]);
        acc = fmaf(hA, __int_as_float(eA.y), acc);
        acc = fmaf(hB, __int_as_float(eB.y), acc);
        acc = fmaf(hC, __int_as_float(eC.y), acc);
        acc = fmaf(hD, __int_as_float(eD.y), acc);
        acc = fmaf(hE, __int_as_float(eE.y), acc);
        acc = fmaf(hF, __int_as_float(eF.y), acc);
        acc = fmaf(hG, __int_as_float(eG.y), acc);
        acc = fmaf(hH, __int_as_float(eH.y), acc);
    }
    for (; k + 3 < s1; k += 4) {
        int2 eA = edges[k], eB = edges[k+1], eC = edges[k+2], eD = edges[k+3];
        float hA = __bfloat162float(Hbf[(size_t)eA.x * DIM + j]);
        float hB = __bfloat162float(Hbf[(size_t)eB.x * DIM + j]);
        float hC = __bfloat162float(Hbf[(size_t)eC.x * DIM + j]);
        float hD = __bfloat162float(Hbf[(size_t)eD.x * DIM + j]);
        acc = fmaf(hA, __int_as_float(eA.y), acc);
        acc = fmaf(hB, __int_as_float(eB.y), acc);
        acc = fmaf(hC, __int_as_float(eC.y), acc);
        acc = fmaf(hD, __int_as_float(eD.y), acc);
    }
    for (; k < s1; ++k) {
        int2 eA = edges[k];
        acc = fmaf(__bfloat162float(Hbf[(size_t)eA.x * DIM + j]), __int_as_float(eA.y), acc);
    }
    acc += bias[j];
    Y[(size_t)node * DIM + j] = fmaxf(acc, 0.f);
}

// ---- fused mean-pool + FC: one block per graph, batch is sorted ----

__global__ __launch_bounds__(256) void pool_fc(const float* __restrict__ H,
                                               const int* __restrict__ batch,
                                               const float* __restrict__ fcW,
                                               const float* __restrict__ fcb,
                                               float* __restrict__ out) {
    __shared__ float part[4][64];
    __shared__ float mean[64];
    int g = blockIdx.x;
    int lo = 0, hi = N_NODES;
    while (lo < hi) { int mid = (lo + hi) >> 1; if (batch[mid] < g) lo = mid + 1; else hi = mid; }
    int start = lo;
    hi = N_NODES;
    while (lo < hi) { int mid = (lo + hi) >> 1; if (batch[mid] < g + 1) lo = mid + 1; else hi = mid; }
    int end = lo;

    int wave = threadIdx.x >> 6, j = threadIdx.x & 63;
    float acc = 0.f;
    for (int n = start + wave; n < end; n += 4)
        acc += H[(size_t)n * DIM + j];
    part[wave][j] = acc;
    __syncthreads();
    if (wave == 0) {
        float s = part[0][j] + part[1][j] + part[2][j] + part[3][j];
        mean[j] = s / fmaxf((float)(end - start), 1.0f);
    }
    __syncthreads();
    if (threadIdx.x < ODIM) {
        int jj = threadIdx.x;
        float a = fcb[jj];
#pragma unroll
        for (int k = 0; k < DIM; ++k) a = fmaf(mean[k], fcW[k * ODIM + jj], a);
        out[g * ODIM + jj] = a;
    }
}

extern "C" void kernel_launch(void* const* d_in, const int* in_sizes, int n_in,
                              void* d_out, int out_size, void* d_ws, size_t ws_size,
                              hipStream_t stream) {
    const float* x    = (const float*)d_in[0];
    const float* W1   = (const float*)d_in[1];
    const float* b1   = (const float*)d_in[2];
    const float* W2   = (const float*)d_in[3];
    const float* b2   = (const float*)d_in[4];
    const float* fcW  = (const float*)d_in[5];
    const float* fcb  = (const float*)d_in[6];
    const int*   eidx = (const int*)d_in[7];
    const int*   batch= (const int*)d_in[8];
    const int* esrc = eidx;
    const int* edst = eidx + N_EDGES;
    float* out = (float*)d_out;

    char* ws = (char*)d_ws;
    size_t o = 0;
    auto alloc = [&](size_t bytes) {
        void* p = ws + o;
        o += (bytes + 255) & ~(size_t)255;
        return p;
    };
    float* bufA     = (float*)alloc((size_t)N_NODES * DIM * 4);
    float* bufB     = (float*)alloc((size_t)N_NODES * DIM * 4);
    __hip_bfloat16* bufbf = (__hip_bfloat16*)alloc((size_t)N_NODES * DIM * 2);
    int*   cnt      = (int*)  alloc((size_t)N_NODES * 4);
    int*   off      = (int*)  alloc((size_t)(N_NODES + 1) * 4);
    int*   cursor   = (int*)  alloc((size_t)N_NODES * 4);
    float* inv_sqrt = (float*)alloc((size_t)N_NODES * 4);
    float* invdeg   = (float*)alloc((size_t)N_NODES * 4);
    int2*  edges    = (int2*) alloc((size_t)N_EDGES * 8);
    int*   blocksum = (int*)  alloc((size_t)SCAN_NB * 4);
    int*   blockbase= (int*)  alloc((size_t)SCAN_NB * 4);

    hipMemsetAsync(cnt, 0, (size_t)N_NODES * 4, stream);

    count_deg<<<(N_EDGES + 255) / 256, 256, 0, stream>>>(edst, cnt);
    scan_p1<<<SCAN_NB, 256, 0, stream>>>(cnt, blocksum);
    scan_p2<<<1, 256, 0, stream>>>(blocksum, blockbase, off);
    scan_p3<<<SCAN_NB, 256, 0, stream>>>(cnt, blockbase, off, cursor, inv_sqrt, invdeg);
    scatter_edges<<<((N_EDGES + 255) / 256) * NXCD, 256, 0, stream>>>(esrc, edst, inv_sqrt, cursor, edges);

    gemm64<<<(N_NODES + 31) / 32, 256, 0, stream>>>(x, W1, bufA, bufbf, N_NODES);
    aggregate<<<(N_NODES + 3) / 4, 256, 0, stream>>>(bufA, bufbf, off, edges, invdeg, b1, bufB);
    gemm64<<<(N_NODES + 31) / 32, 256, 0, stream>>>(bufB, W2, bufA, bufbf, N_NODES);
    aggregate<<<(N_NODES + 3) / 4, 256, 0, stream>>>(bufA, bufbf, off, edges, invdeg, b2, bufB);

    pool_fc<<<N_GRAPHS, 256, 0, stream>>>(bufB, batch, fcW, fcb, out);
}

// Round 9
// 299.342 us; speedup vs baseline: 1.9306x; 1.0126x over previous
//
#include <hip/hip_runtime.h>
#include <hip/hip_bf16.h>

#define N_NODES 50000
#define N_EDGES 800000
#define DIM 64
#define ODIM 32
#define N_GRAPHS 512
#define SCAN_NB ((N_NODES + 255) / 256)   // 196
#define NXCD 8
#define DST_RANGE ((N_NODES + NXCD - 1) / NXCD)   // 6250

// ---- graph prep: counting-sort edges by dst into CSR ----

__global__ void count_deg(const int* __restrict__ dst, int* __restrict__ cnt) {
    int e = blockIdx.x * blockDim.x + threadIdx.x;
    if (e < N_EDGES) atomicAdd(&cnt[__builtin_nontemporal_load(&dst[e])], 1);
}

// ---- 2-phase exclusive scan over cnt[N_NODES] ----

__global__ __launch_bounds__(256) void scan_p1(const int* __restrict__ cnt,
                                               int* __restrict__ blocksum) {
    __shared__ int ws[4];
    int i = blockIdx.x * 256 + threadIdx.x;
    int v = (i < N_NODES) ? cnt[i] : 0;
    for (int d = 32; d > 0; d >>= 1) v += __shfl_down(v, d, 64);
    int lane = threadIdx.x & 63, wid = threadIdx.x >> 6;
    if (lane == 0) ws[wid] = v;
    __syncthreads();
    if (threadIdx.x == 0) blocksum[blockIdx.x] = ws[0] + ws[1] + ws[2] + ws[3];
}

__global__ __launch_bounds__(256) void scan_p3(const int* __restrict__ cnt,
                                               const int* __restrict__ blocksum,
                                               int* __restrict__ off,
                                               int* __restrict__ cursor,
                                               float* __restrict__ inv_sqrt,
                                               float* __restrict__ invdeg) {
    __shared__ int wtot[4];
    __shared__ int bb[SCAN_NB + 1];
    {
        int t = threadIdx.x;
        int v = (t < SCAN_NB) ? blocksum[t] : 0;
        int lane = t & 63, wid = t >> 6;
        int incl = v;
        for (int d = 1; d < 64; d <<= 1) {
            int u = __shfl_up(incl, d, 64);
            if (lane >= d) incl += u;
        }
        if (lane == 63) wtot[wid] = incl;
        __syncthreads();
        int base = 0;
        for (int w = 0; w < wid; ++w) base += wtot[w];
        incl += base;
        if (t <= SCAN_NB) bb[t] = incl - v;   // exclusive; bb[SCAN_NB] = total
        __syncthreads();
    }
    if (blockIdx.x == 0 && threadIdx.x == 0) off[N_NODES] = bb[SCAN_NB];
    __syncthreads();

    int i = blockIdx.x * 256 + threadIdx.x;
    int v = (i < N_NODES) ? cnt[i] : 0;
    int lane = threadIdx.x & 63, wid = threadIdx.x >> 6;
    int incl = v;
    for (int d = 1; d < 64; d <<= 1) {
        int u = __shfl_up(incl, d, 64);
        if (lane >= d) incl += u;
    }
    __syncthreads();
    if (lane == 63) wtot[wid] = incl;
    __syncthreads();
    int base = bb[blockIdx.x];
    for (int w = 0; w < wid; ++w) base += wtot[w];
    int excl = base + incl - v;
    if (i < N_NODES) {
        off[i] = excl; cursor[i] = excl;
        float d = (float)(v + 1);   // self-loop
        inv_sqrt[i] = rsqrtf(d);
        invdeg[i]   = 1.0f / d;
    }
}

// XCD-partitioned scatter: block = (chunk, range); blockIdx%8 -> XCD round-robin
__global__ void scatter_edges(const int* __restrict__ src, const int* __restrict__ dst,
                              const float* __restrict__ inv_sqrt,
                              int* __restrict__ cursor,
                              int2* __restrict__ edges) {
    int chunk = blockIdx.x >> 3;
    int range = blockIdx.x & 7;
    int e = chunk * 256 + threadIdx.x;
    if (e >= N_EDGES) return;
    int d = dst[e];
    int lo = range * DST_RANGE;
    if ((unsigned)(d - lo) < (unsigned)DST_RANGE) {
        int s = src[e];
        int pos = atomicAdd(&cursor[d], 1);
        float w = inv_sqrt[s] * inv_sqrt[d];
        edges[pos] = make_int2(s, __float_as_int(w));
    }
}

// ---- h = X @ W  (N x 64 @ 64 x 64); fp32 Y + bf16 copy ----
// 8-row register accumulation: each W float4 read once from LDS, applied to 8 rows.

__global__ __launch_bounds__(256) void gemm64(const float* __restrict__ X,
                                              const float* __restrict__ W,
                                              float* __restrict__ Y,
                                              __hip_bfloat16* __restrict__ Ybf,
                                              int nrows) {
    __shared__ float Ws[64 * 68];
    for (int i = threadIdx.x; i < 64 * 64; i += 256) {
        int k = i >> 6, j = i & 63;
        Ws[j * 68 + k] = W[i];
    }
    __syncthreads();
    int wave = threadIdx.x >> 6;
    int j    = threadIdx.x & 63;
    const float* wrow = &Ws[j * 68];
    int row0 = (blockIdx.x * 4 + wave) * 8;
    if (row0 >= nrows) return;
    float acc[8] = {0,0,0,0,0,0,0,0};
    const float* x0 = X + (size_t)row0 * DIM;   // wave-uniform
    if (row0 + 8 <= nrows) {
#pragma unroll
        for (int k4 = 0; k4 < 16; ++k4) {
            float4 w4 = *(const float4*)&wrow[k4 * 4];
#pragma unroll
            for (int r = 0; r < 8; ++r) {
                float4 x4 = *(const float4*)&x0[r * DIM + k4 * 4];
                acc[r] = fmaf(x4.x, w4.x, acc[r]);
                acc[r] = fmaf(x4.y, w4.y, acc[r]);
                acc[r] = fmaf(x4.z, w4.z, acc[r]);
                acc[r] = fmaf(x4.w, w4.w, acc[r]);
            }
        }
#pragma unroll
        for (int r = 0; r < 8; ++r) {
            Y[(size_t)(row0 + r) * DIM + j]   = acc[r];
            Ybf[(size_t)(row0 + r) * DIM + j] = __float2bfloat16(acc[r]);
        }
    } else {
        int nr = nrows - row0;
        for (int k4 = 0; k4 < 16; ++k4) {
            float4 w4 = *(const float4*)&wrow[k4 * 4];
            for (int r = 0; r < nr; ++r) {
                float4 x4 = *(const float4*)&x0[r * DIM + k4 * 4];
                acc[r] = fmaf(x4.x, w4.x, acc[r]);
                acc[r] = fmaf(x4.y, w4.y, acc[r]);
                acc[r] = fmaf(x4.z, w4.z, acc[r]);
                acc[r] = fmaf(x4.w, w4.w, acc[r]);
            }
        }
        for (int r = 0; r < nr; ++r) {
            Y[(size_t)(row0 + r) * DIM + j]   = acc[r];
            Ybf[(size_t)(row0 + r) * DIM + j] = __float2bfloat16(acc[r]);
        }
    }
}

// ---- fused: layer-1 aggregate (+bias1, relu) THEN layer-2 gemm (@W2) ----
// Reads bf1 (layer-1 h), writes Y/Ybf2 (layer-2 h). SEPARATE buffers: no alias.

__global__ __launch_bounds__(256) void agg_gemm(const float* __restrict__ H,
                                                const __hip_bfloat16* __restrict__ Hbf,
                                                const int* __restrict__ off,
                                                const int2* __restrict__ edges,
                                                const float* __restrict__ invdeg,
                                                const float* __restrict__ bias,
                                                const float* __restrict__ W2,
                                                float* __restrict__ Y,
                                                __hip_bfloat16* __restrict__ Ybf2) {
    __shared__ float Ws[64 * 68];
    __shared__ float rowbuf[4][64];
    for (int i = threadIdx.x; i < 64 * 64; i += 256) {
        int k = i >> 6, j = i & 63;
        Ws[j * 68 + k] = W2[i];
    }
    __syncthreads();
    int wave = threadIdx.x >> 6;
    int j    = threadIdx.x & 63;
    int node = blockIdx.x * 4 + wave;
    if (node < N_NODES) {
        float acc = H[(size_t)node * DIM + j] * invdeg[node];
        int s0 = off[node], s1 = off[node + 1];
        int k = s0;
        for (; k + 7 < s1; k += 8) {
            int2 eA = edges[k],   eB = edges[k+1], eC = edges[k+2], eD = edges[k+3];
            int2 eE = edges[k+4], eF = edges[k+5], eG = edges[k+6], eH = edges[k+7];
            float hA = __bfloat162float(Hbf[(size_t)eA.x * DIM + j]);
            float hB = __bfloat162float(Hbf[(size_t)eB.x * DIM + j]);
            float hC = __bfloat162float(Hbf[(size_t)eC.x * DIM + j]);
            float hD = __bfloat162float(Hbf[(size_t)eD.x * DIM + j]);
            float hE = __bfloat162float(Hbf[(size_t)eE.x * DIM + j]);
            float hF = __bfloat162float(Hbf[(size_t)eF.x * DIM + j]);
            float hG = __bfloat162float(Hbf[(size_t)eG.x * DIM + j]);
            float hH = __bfloat162float(Hbf[(size_t)eH.x * DIM + j]);
            acc = fmaf(hA, __int_as_float(eA.y), acc);
            acc = fmaf(hB, __int_as_float(eB.y), acc);
            acc = fmaf(hC, __int_as_float(eC.y), acc);
            acc = fmaf(hD, __int_as_float(eD.y), acc);
            acc = fmaf(hE, __int_as_float(eE.y), acc);
            acc = fmaf(hF, __int_as_float(eF.y), acc);
            acc = fmaf(hG, __int_as_float(eG.y), acc);
            acc = fmaf(hH, __int_as_float(eH.y), acc);
        }
        for (; k < s1; ++k) {
            int2 eA = edges[k];
            acc = fmaf(__bfloat162float(Hbf[(size_t)eA.x * DIM + j]), __int_as_float(eA.y), acc);
        }
        rowbuf[wave][j] = fmaxf(acc + bias[j], 0.f);
    }
    __syncthreads();
    if (node < N_NODES) {
        const float* hr   = rowbuf[wave];
        const float* wrow = &Ws[j * 68];
        float acc2 = 0.f;
#pragma unroll
        for (int k4 = 0; k4 < 16; ++k4) {
            float4 h4 = *(const float4*)&hr[k4 * 4];     // broadcast
            float4 w4 = *(const float4*)&wrow[k4 * 4];
            acc2 = fmaf(h4.x, w4.x, acc2);
            acc2 = fmaf(h4.y, w4.y, acc2);
            acc2 = fmaf(h4.z, w4.z, acc2);
            acc2 = fmaf(h4.w, w4.w, acc2);
        }
        Y[(size_t)node * DIM + j]    = acc2;
        Ybf2[(size_t)node * DIM + j] = __float2bfloat16(acc2);
    }
}

// ---- layer-2 aggregate (+bias2, relu) ----

__global__ __launch_bounds__(256) void aggregate(const float* __restrict__ H,
                                                 const __hip_bfloat16* __restrict__ Hbf,
                                                 const int* __restrict__ off,
                                                 const int2* __restrict__ edges,
                                                 const float* __restrict__ invdeg,
                                                 const float* __restrict__ bias,
                                                 float* __restrict__ Y) {
    int node = blockIdx.x * 4 + (threadIdx.x >> 6);
    int j    = threadIdx.x & 63;
    if (node >= N_NODES) return;
    float acc = H[(size_t)node * DIM + j] * invdeg[node];
    int s0 = off[node], s1 = off[node + 1];
    int k = s0;
    for (; k + 7 < s1; k += 8) {
        int2 eA = edges[k],   eB = edges[k+1], eC = edges[k+2], eD = edges[k+3];
        int2 eE = edges[k+4], eF = edges[k+5], eG = edges[k+6], eH = edges[k+7];
        float hA = __bfloat162float(Hbf[(size_t)eA.x * DIM + j]);
        float hB = __bfloat162float(Hbf[(size_t)eB.x * DIM + j]);
        float hC = __bfloat162float(Hbf[(size_t)eC.x * DIM + j]);
        float hD = __bfloat162float(Hbf[(size_t)eD.x * DIM + j]);
        float hE = __bfloat162float(Hbf[(size_t)eE.x * DIM + j]);
        float hF = __bfloat162float(Hbf[(size_t)eF.x * DIM + j]);
        float hG = __bfloat162float(Hbf[(size_t)eG.x * DIM + j]);
        float hH = __bfloat162float(Hbf[(size_t)eH.x * DIM + j]);
        acc = fmaf(hA, __int_as_float(eA.y), acc);
        acc = fmaf(hB, __int_as_float(eB.y), acc);
        acc = fmaf(hC, __int_as_float(eC.y), acc);
        acc = fmaf(hD, __int_as_float(eD.y), acc);
        acc = fmaf(hE, __int_as_float(eE.y), acc);
        acc = fmaf(hF, __int_as_float(eF.y), acc);
        acc = fmaf(hG, __int_as_float(eG.y), acc);
        acc = fmaf(hH, __int_as_float(eH.y), acc);
    }
    for (; k < s1; ++k) {
        int2 eA = edges[k];
        acc = fmaf(__bfloat162float(Hbf[(size_t)eA.x * DIM + j]), __int_as_float(eA.y), acc);
    }
    acc += bias[j];
    Y[(size_t)node * DIM + j] = fmaxf(acc, 0.f);
}

// ---- fused mean-pool + FC: one block per graph, batch is sorted ----

__global__ __launch_bounds__(256) void pool_fc(const float* __restrict__ H,
                                               const int* __restrict__ batch,
                                               const float* __restrict__ fcW,
                                               const float* __restrict__ fcb,
                                               float* __restrict__ out) {
    __shared__ float part[4][64];
    __shared__ float mean[64];
    int g = blockIdx.x;
    int lo = 0, hi = N_NODES;
    while (lo < hi) { int mid = (lo + hi) >> 1; if (batch[mid] < g) lo = mid + 1; else hi = mid; }
    int start = lo;
    hi = N_NODES;
    while (lo < hi) { int mid = (lo + hi) >> 1; if (batch[mid] < g + 1) lo = mid + 1; else hi = mid; }
    int end = lo;

    int wave = threadIdx.x >> 6, j = threadIdx.x & 63;
    float acc = 0.f;
    for (int n = start + wave; n < end; n += 4)
        acc += H[(size_t)n * DIM + j];
    part[wave][j] = acc;
    __syncthreads();
    if (wave == 0) {
        float s = part[0][j] + part[1][j] + part[2][j] + part[3][j];
        mean[j] = s / fmaxf((float)(end - start), 1.0f);
    }
    __syncthreads();
    if (threadIdx.x < ODIM) {
        int jj = threadIdx.x;
        float a = fcb[jj];
#pragma unroll
        for (int k = 0; k < DIM; ++k) a = fmaf(mean[k], fcW[k * ODIM + jj], a);
        out[g * ODIM + jj] = a;
    }
}

extern "C" void kernel_launch(void* const* d_in, const int* in_sizes, int n_in,
                              void* d_out, int out_size, void* d_ws, size_t ws_size,
                              hipStream_t stream) {
    const float* x    = (const float*)d_in[0];
    const float* W1   = (const float*)d_in[1];
    const float* b1   = (const float*)d_in[2];
    const float* W2   = (const float*)d_in[3];
    const float* b2   = (const float*)d_in[4];
    const float* fcW  = (const float*)d_in[5];
    const float* fcb  = (const float*)d_in[6];
    const int*   eidx = (const int*)d_in[7];
    const int*   batch= (const int*)d_in[8];
    const int* esrc = eidx;
    const int* edst = eidx + N_EDGES;
    float* out = (float*)d_out;

    char* ws = (char*)d_ws;
    size_t o = 0;
    auto alloc = [&](size_t bytes) {
        void* p = ws + o;
        o += (bytes + 255) & ~(size_t)255;
        return p;
    };
    float* bufA     = (float*)alloc((size_t)N_NODES * DIM * 4);
    float* bufB     = (float*)alloc((size_t)N_NODES * DIM * 4);
    __hip_bfloat16* bf1 = (__hip_bfloat16*)alloc((size_t)N_NODES * DIM * 2);
    __hip_bfloat16* bf2 = (__hip_bfloat16*)alloc((size_t)N_NODES * DIM * 2);
    int*   cnt      = (int*)  alloc((size_t)N_NODES * 4);
    int*   off      = (int*)  alloc((size_t)(N_NODES + 1) * 4);
    int*   cursor   = (int*)  alloc((size_t)N_NODES * 4);
    float* inv_sqrt = (float*)alloc((size_t)N_NODES * 4);
    float* invdeg   = (float*)alloc((size_t)N_NODES * 4);
    int2*  edges    = (int2*) alloc((size_t)N_EDGES * 8);
    int*   blocksum = (int*)  alloc((size_t)SCAN_NB * 4);

    hipMemsetAsync(cnt, 0, (size_t)N_NODES * 4, stream);

    count_deg<<<(N_EDGES + 255) / 256, 256, 0, stream>>>(edst, cnt);
    scan_p1<<<SCAN_NB, 256, 0, stream>>>(cnt, blocksum);
    scan_p3<<<SCAN_NB, 256, 0, stream>>>(cnt, blocksum, off, cursor, inv_sqrt, invdeg);
    scatter_edges<<<((N_EDGES + 255) / 256) * NXCD, 256, 0, stream>>>(esrc, edst, inv_sqrt, cursor, edges);

    gemm64<<<(N_NODES + 31) / 32, 256, 0, stream>>>(x, W1, bufA, bf1, N_NODES);
    agg_gemm<<<(N_NODES + 3) / 4, 256, 0, stream>>>(bufA, bf1, off, edges, invdeg, b1, W2, bufB, bf2);
    aggregate<<<(N_NODES + 3) / 4, 256, 0, stream>>>(bufB, bf2, off, edges, invdeg, b2, bufA);

    pool_fc<<<N_GRAPHS, 256, 0, stream>>>(bufA, batch, fcW, fcb, out);
}